// Round 3
// baseline (249.158 us; speedup 1.0000x reference)
//
#include <hip/hip_runtime.h>

#define NN 50000
#define NE 600000
#define DIM 128
#define NB_N 196   // ceil(50000/256)
#define NB_E2 1172 // ceil(300000/256) edge-pair blocks
#define TILES 3125 // 50000/16
#define ROWW 136   // LDS row pitch in u16 (128 + 8 pad)
#define NEPAD (NE + 16 * NN + 64)  // rows padded to multiple of 16, min 16

// k_fill block roles
#define B_PAD NB_N                  // 196 pad blocks
#define B_SENT (NB_E2 + B_PAD)      // 1368
#define B_GEMM0 (B_SENT + 1)        // 1369
#define NB_GEMM 782                 // ceil(3125/4)
#define NB_FILL (B_GEMM0 + NB_GEMM) // 2151

typedef unsigned short u16;
typedef unsigned int u32;
typedef __attribute__((ext_vector_type(8))) short bf16x8;
typedef __attribute__((ext_vector_type(4))) float f32x4;
typedef __attribute__((ext_vector_type(2))) float f32x2;

__device__ __forceinline__ u16 f2bf(float f) {
    u32 u = __builtin_bit_cast(u32, f);
    u32 r = (u + 0x7FFFu + ((u >> 16) & 1u)) >> 16;
    return (u16)r;
}
__device__ __forceinline__ float bflo(u32 w) { return __builtin_bit_cast(float, w << 16); }
__device__ __forceinline__ float bfhi(u32 w) { return __builtin_bit_cast(float, w & 0xffff0000u); }
__device__ __forceinline__ f32x2 unp(u32 w) {
    f32x2 v; v.x = bflo(w); v.y = bfhi(w); return v;
}
__device__ __forceinline__ int pad16(int d) {
    int p = (d + 15) & ~15;
    return p < 16 ? 16 : p;
}

// ---- count + rank + weight cast -------------------------------------------
// blocks [0, NB_E2): 2 edges/thread: in-degree count; rank[e] = slot in dst row
// blocks [NB_E2, NB_E2+192): Wt[layer][n][k] = bf16(W[layer][k][n])
__global__ __launch_bounds__(256) void k_count(const int* __restrict__ ei,
                                               int* __restrict__ deg,
                                               int* __restrict__ rank,
                                               const float* __restrict__ W0,
                                               const float* __restrict__ W1,
                                               const float* __restrict__ W2,
                                               u16* __restrict__ Wt) {
    int b = blockIdx.x;
    if (b >= NB_E2) {  // weight cast: 192 blocks x 256 = 49152 = 3*16384
        int idx = (b - NB_E2) * 256 + threadIdx.x;
        int l = idx >> 14, rem = idx & 16383;
        int n = rem >> 7, k = rem & 127;
        const float* W = (l == 0) ? W0 : ((l == 1) ? W1 : W2);
        Wt[idx] = f2bf(W[k * 128 + n]);
        return;
    }
    __shared__ int s64;
    if (threadIdx.x == 0) {
        int o = 0;
#pragma unroll
        for (int j = 0; j < 16; j++) o |= ei[2 * j + 1];  // int64 => high words 0
        s64 = (o == 0);
    }
    __syncthreads();
    int p = b * 256 + threadIdx.x;  // edge pair index
    int ebase = 2 * p;
    if (ebase >= NE) return;
    int d0, d1;
    if (s64) {
        int4 dd = *(const int4*)(ei + 2 * (NE + ebase));
        d0 = dd.x; d1 = dd.z;
    } else {
        int2 dd = *(const int2*)(ei + NE + ebase);
        d0 = dd.x; d1 = dd.y;
    }
    int r0 = atomicAdd(&deg[d0], 1);
    int r1 = atomicAdd(&deg[d1], 1);
    *(int2*)(rank + ebase) = make_int2(r0, r1);
}

// ---- scanA: per-block exclusive scan of pad16(deg), raw block sums --------
__global__ __launch_bounds__(256) void k_scanA(const int* __restrict__ deg,
                                               int* __restrict__ rp8,
                                               int* __restrict__ bsum) {
    __shared__ int buf[256];
    int t = threadIdx.x, i = blockIdx.x * 256 + t;
    int v = (i < NN) ? pad16(deg[i]) : 0;
    buf[t] = v;
    __syncthreads();
    for (int off = 1; off < 256; off <<= 1) {
        int x = (t >= off) ? buf[t - off] : 0;
        __syncthreads();
        buf[t] += x;
        __syncthreads();
    }
    if (i < NN) rp8[i] = buf[t] - v;
    if (t == 255) bsum[blockIdx.x] = buf[255];
}

// ---- scanC (merged scanB): each block reduces bsum itself, applies + dinv --
__global__ __launch_bounds__(256) void k_scanC(const int* __restrict__ deg,
                                               int* __restrict__ rp8,
                                               const int* __restrict__ bsum,
                                               float* __restrict__ dinv) {
    __shared__ int soff, stot;
    if (threadIdx.x < 64) {
        int accP = 0, accT = 0;
        for (int j = threadIdx.x; j < NB_N; j += 64) {
            int v = bsum[j];
            accT += v;
            if (j < (int)blockIdx.x) accP += v;
        }
        for (int off = 1; off < 64; off <<= 1) {
            accP += __shfl_xor(accP, off, 64);
            accT += __shfl_xor(accT, off, 64);
        }
        if (threadIdx.x == 0) { soff = accP; stot = accT; }
    }
    __syncthreads();
    int i = blockIdx.x * 256 + threadIdx.x;
    if (i < NN) {
        rp8[i] += soff;
        dinv[i] = rsqrtf((float)(deg[i] + 1));  // +1 self loop
    }
    if (i == 0) rp8[NN] = stot;
}

// ---- fill CSR + pad sentinels + zero sentinel rows + layer-1 GEMM ---------
__global__ __launch_bounds__(256) void k_fill(const int* __restrict__ ei,
                                              const int* __restrict__ rp8,
                                              const int* __restrict__ rank,
                                              const int* __restrict__ deg,
                                              int* __restrict__ recs,
                                              const float* __restrict__ x,
                                              const u16* __restrict__ Wt,
                                              const float* __restrict__ dinv,
                                              u16* __restrict__ hwA,
                                              u16* __restrict__ hwB) {
    int b = blockIdx.x;
    if (b < NB_E2) {  // CSR fill, 2 edges/thread (no atomics: rank precomputed)
        __shared__ int s64;
        if (threadIdx.x == 0) {
            int o = 0;
#pragma unroll
            for (int j = 0; j < 16; j++) o |= ei[2 * j + 1];
            s64 = (o == 0);
        }
        __syncthreads();
        int p = b * 256 + threadIdx.x;
        int ebase = 2 * p;
        if (ebase >= NE) return;
        int s0, s1, d0, d1;
        if (s64) {
            int4 ss = *(const int4*)(ei + 2 * ebase);
            int4 dd = *(const int4*)(ei + 2 * (NE + ebase));
            s0 = ss.x; s1 = ss.z; d0 = dd.x; d1 = dd.z;
        } else {
            int2 ss = *(const int2*)(ei + ebase);
            int2 dd = *(const int2*)(ei + NE + ebase);
            s0 = ss.x; s1 = ss.y; d0 = dd.x; d1 = dd.y;
        }
        int2 rk = *(const int2*)(rank + ebase);
        recs[rp8[d0] + rk.x] = s0;
        recs[rp8[d1] + rk.y] = s1;
        return;
    }
    if (b < B_SENT) {  // pad entries -> sentinel node NN
        int i = (b - NB_E2) * 256 + threadIdx.x;
        if (i < NN) {
            int rp = rp8[i], d = deg[i], p = pad16(d);
            for (int j = d; j < p; j++) recs[rp + j] = NN;
        }
        return;
    }
    if (b == B_SENT) {  // zero sentinel rows (256 B each)
        if (threadIdx.x < 64) {
            ((u32*)(hwA + (size_t)NN * DIM))[threadIdx.x] = 0;
            ((u32*)(hwB + (size_t)NN * DIM))[threadIdx.x] = 0;
        }
        return;
    }
    // layer-1 GEMM: hwA[v] = bf16(dinv[v] * (bf16(x[v]) @ W0))
    // depends only on x, Wt (k_count), dinv (k_scanC) -> overlaps CSR fill.
    int lane = threadIdx.x & 63;
    int tile = (b - B_GEMM0) * 4 + (threadIdx.x >> 6);
    if (tile >= TILES) return;
    int r = lane & 15, q = lane >> 4;
    long rowbase = (long)tile * 16;
    bf16x8 Af[4];
#pragma unroll
    for (int kc = 0; kc < 4; kc++) {
        const float4* p = (const float4*)(x + (rowbase + r) * 128 + kc * 32 + q * 8);
        float4 t0 = p[0], t1 = p[1];
        bf16x8 a;
        a[0] = (short)f2bf(t0.x); a[1] = (short)f2bf(t0.y);
        a[2] = (short)f2bf(t0.z); a[3] = (short)f2bf(t0.w);
        a[4] = (short)f2bf(t1.x); a[5] = (short)f2bf(t1.y);
        a[6] = (short)f2bf(t1.z); a[7] = (short)f2bf(t1.w);
        Af[kc] = a;
    }
    float dv[4];
#pragma unroll
    for (int i = 0; i < 4; i++) dv[i] = dinv[rowbase + q * 4 + i];
#pragma unroll
    for (int nt = 0; nt < 8; nt++) {
        f32x4 acc = {0.f, 0.f, 0.f, 0.f};
#pragma unroll
        for (int kc = 0; kc < 4; kc++) {
            bf16x8 Bf = *(const bf16x8*)(Wt + ((nt * 16 + r) << 7) + kc * 32 + q * 8);
            acc = __builtin_amdgcn_mfma_f32_16x16x32_bf16(Af[kc], Bf, acc, 0, 0, 0);
        }
#pragma unroll
        for (int i = 0; i < 4; i++)
            hwA[(rowbase + q * 4 + i) * 128 + nt * 16 + r] = f2bf(dv[i] * acc[i]);
    }
}

// ---- aggregation core: wave = 4 nodes in one pass. Group g handles edges
// {4g..4g+3} of each 16-entry chunk. Round 0 (all nodes active, pad16
// guarantees a full chunk) is software-pipelined across nodes; rare extra
// rounds run in a wave-uniform-branch tail that skips finished nodes.
__device__ __forceinline__ void acc8(f32x2* a, uint4 u) {
    a[0] += unp(u.x); a[1] += unp(u.y); a[2] += unp(u.z); a[3] += unp(u.w);
}

__device__ __forceinline__ uint4 ldrow(const u16* __restrict__ hw, int s, int r) {
    return *(const uint4*)(hw + (size_t)(u32)s * DIM + r * 8);
}

__device__ __forceinline__ void agg_quad(const u16* __restrict__ hw,
                                         const int* __restrict__ rp8,
                                         const int* __restrict__ recs,
                                         int v0, int g, int r,
                                         f32x2* A0, f32x2* A1, f32x2* A2, f32x2* A3) {
    int4 rr = *(const int4*)(rp8 + v0);  // v0 % 4 == 0
    int n3 = rp8[v0 + 4];
    int e0 = rr.x, e1 = rr.y, e2 = rr.z, e3 = rr.w;
    int n0 = e1, n1 = e2, n2 = e3;
    const int go = 4 * g;
    int4 q0 = *(const int4*)(recs + e0 + go);
    int4 q1 = *(const int4*)(recs + e1 + go);
    int4 q2 = *(const int4*)(recs + e2 + go);
    int4 q3 = *(const int4*)(recs + e3 + go);
    uint4 s0 = ldrow(hw, v0, r);
    uint4 s1 = ldrow(hw, v0 + 1, r);
    uint4 s2 = ldrow(hw, v0 + 2, r);
    uint4 s3 = ldrow(hw, v0 + 3, r);
    float m = (g == 0) ? 1.0f : 0.0f;  // self term counted once
    A0[0] = m * unp(s0.x); A0[1] = m * unp(s0.y); A0[2] = m * unp(s0.z); A0[3] = m * unp(s0.w);
    A1[0] = m * unp(s1.x); A1[1] = m * unp(s1.y); A1[2] = m * unp(s1.z); A1[3] = m * unp(s1.w);
    A2[0] = m * unp(s2.x); A2[1] = m * unp(s2.y); A2[2] = m * unp(s2.z); A2[3] = m * unp(s2.w);
    A3[0] = m * unp(s3.x); A3[1] = m * unp(s3.y); A3[2] = m * unp(s3.z); A3[3] = m * unp(s3.w);

    // ---- round 0: every node has >= 16 entries (pad16) -> no clamps.
    // Pipelined: keep at most 2 nodes' loads in flight (8 uint4 live).
    uint4 u00 = ldrow(hw, q0.x, r), u01 = ldrow(hw, q0.y, r);
    uint4 u02 = ldrow(hw, q0.z, r), u03 = ldrow(hw, q0.w, r);
    uint4 u10 = ldrow(hw, q1.x, r), u11 = ldrow(hw, q1.y, r);
    uint4 u12 = ldrow(hw, q1.z, r), u13 = ldrow(hw, q1.w, r);
    e0 += 16; e1 += 16; e2 += 16; e3 += 16;
    acc8(A0, u00); acc8(A0, u01); acc8(A0, u02); acc8(A0, u03);
    uint4 u20 = ldrow(hw, q2.x, r), u21 = ldrow(hw, q2.y, r);
    uint4 u22 = ldrow(hw, q2.z, r), u23 = ldrow(hw, q2.w, r);
    acc8(A1, u10); acc8(A1, u11); acc8(A1, u12); acc8(A1, u13);
    uint4 u30 = ldrow(hw, q3.x, r), u31 = ldrow(hw, q3.y, r);
    uint4 u32_ = ldrow(hw, q3.z, r), u33 = ldrow(hw, q3.w, r);
    q0 = *(const int4*)(recs + min(e0, n0 - 16) + go);
    q1 = *(const int4*)(recs + min(e1, n1 - 16) + go);
    q2 = *(const int4*)(recs + min(e2, n2 - 16) + go);
    q3 = *(const int4*)(recs + min(e3, n3 - 16) + go);
    acc8(A2, u20); acc8(A2, u21); acc8(A2, u22); acc8(A2, u23);
    acc8(A3, u30); acc8(A3, u31); acc8(A3, u32_); acc8(A3, u33);

    // ---- tail rounds (rare): wave-uniform per-node skip
    while ((e0 < n0) | (e1 < n1) | (e2 < n2) | (e3 < n3)) {
        if (e0 < n0) {
            uint4 a = ldrow(hw, q0.x, r), b = ldrow(hw, q0.y, r);
            uint4 c = ldrow(hw, q0.z, r), d = ldrow(hw, q0.w, r);
            e0 += 16;
            q0 = *(const int4*)(recs + min(e0, n0 - 16) + go);
            acc8(A0, a); acc8(A0, b); acc8(A0, c); acc8(A0, d);
        }
        if (e1 < n1) {
            uint4 a = ldrow(hw, q1.x, r), b = ldrow(hw, q1.y, r);
            uint4 c = ldrow(hw, q1.z, r), d = ldrow(hw, q1.w, r);
            e1 += 16;
            q1 = *(const int4*)(recs + min(e1, n1 - 16) + go);
            acc8(A1, a); acc8(A1, b); acc8(A1, c); acc8(A1, d);
        }
        if (e2 < n2) {
            uint4 a = ldrow(hw, q2.x, r), b = ldrow(hw, q2.y, r);
            uint4 c = ldrow(hw, q2.z, r), d = ldrow(hw, q2.w, r);
            e2 += 16;
            q2 = *(const int4*)(recs + min(e2, n2 - 16) + go);
            acc8(A2, a); acc8(A2, b); acc8(A2, c); acc8(A2, d);
        }
        if (e3 < n3) {
            uint4 a = ldrow(hw, q3.x, r), b = ldrow(hw, q3.y, r);
            uint4 c = ldrow(hw, q3.z, r), d = ldrow(hw, q3.w, r);
            e3 += 16;
            q3 = *(const int4*)(recs + min(e3, n3 - 16) + go);
            acc8(A3, a); acc8(A3, b); acc8(A3, c); acc8(A3, d);
        }
    }
}

// combine groups, scale by dinv[d], + bias, relu
__device__ __forceinline__ void combine_scale2(float dv, const float* bias, int r,
                                               f32x2* acc) {
#pragma unroll
    for (int j = 0; j < 4; j++) {
        acc[j].x += __shfl_xor(acc[j].x, 16, 64);
        acc[j].y += __shfl_xor(acc[j].y, 16, 64);
        acc[j].x += __shfl_xor(acc[j].x, 32, 64);
        acc[j].y += __shfl_xor(acc[j].y, 32, 64);
    }
    float4 b0 = ((const float4*)bias)[2 * r];
    float4 b1 = ((const float4*)bias)[2 * r + 1];
    acc[0].x = fmaxf(fmaf(dv, acc[0].x, b0.x), 0.f);
    acc[0].y = fmaxf(fmaf(dv, acc[0].y, b0.y), 0.f);
    acc[1].x = fmaxf(fmaf(dv, acc[1].x, b0.z), 0.f);
    acc[1].y = fmaxf(fmaf(dv, acc[1].y, b0.w), 0.f);
    acc[2].x = fmaxf(fmaf(dv, acc[2].x, b1.x), 0.f);
    acc[2].y = fmaxf(fmaf(dv, acc[2].y, b1.y), 0.f);
    acc[3].x = fmaxf(fmaf(dv, acc[3].x, b1.z), 0.f);
    acc[3].y = fmaxf(fmaf(dv, acc[3].y, b1.w), 0.f);
}

__device__ __forceinline__ uint4 pk8(const f32x2* A) {
    uint4 p;
    p.x = (u32)f2bf(A[0].x) | ((u32)f2bf(A[0].y) << 16);
    p.y = (u32)f2bf(A[1].x) | ((u32)f2bf(A[1].y) << 16);
    p.z = (u32)f2bf(A[2].x) | ((u32)f2bf(A[2].y) << 16);
    p.w = (u32)f2bf(A[3].x) | ((u32)f2bf(A[3].y) << 16);
    return p;
}

// ---- fused: h = relu(dv*agg+b) -> LDS tile -> hw_out = dinv * (h @ W) ------
__global__ __launch_bounds__(256) void k_agg_gemm(const u16* __restrict__ hw_in,
                                                  const int* __restrict__ rp8,
                                                  const int* __restrict__ recs,
                                                  const float* __restrict__ dinv,
                                                  const float* __restrict__ bias,
                                                  const u16* __restrict__ Wt,
                                                  u16* __restrict__ hw_out) {
    __shared__ u16 sm[16 * ROWW];
    int lane = threadIdx.x & 63;
    int w = threadIdx.x >> 6;
    int g = lane >> 4, r = lane & 15;
    int base = blockIdx.x * 16;
    int v0 = base + w * 4;
    f32x2 A0[4], A1[4], A2[4], A3[4];
    agg_quad(hw_in, rp8, recs, v0, g, r, A0, A1, A2, A3);
    float4 dvq = *(const float4*)(dinv + v0);
    combine_scale2(dvq.x, bias, r, A0);
    combine_scale2(dvq.y, bias, r, A1);
    combine_scale2(dvq.z, bias, r, A2);
    combine_scale2(dvq.w, bias, r, A3);
    if (g == 0) {
        int rowa = w * 4;
        *(uint4*)(sm + (rowa + 0) * ROWW + r * 8) = pk8(A0);
        *(uint4*)(sm + (rowa + 1) * ROWW + r * 8) = pk8(A1);
        *(uint4*)(sm + (rowa + 2) * ROWW + r * 8) = pk8(A2);
        *(uint4*)(sm + (rowa + 3) * ROWW + r * 8) = pk8(A3);
    }
    __syncthreads();
    // GEMM: 16x128 LDS tile @ 128x128 W; wave w does n-tiles {2w, 2w+1}
    int q = lane >> 4;
    bf16x8 Af[4];
#pragma unroll
    for (int kc = 0; kc < 4; kc++)
        Af[kc] = *(const bf16x8*)(sm + r * ROWW + kc * 32 + q * 8);
    float dv[4];
#pragma unroll
    for (int i = 0; i < 4; i++) dv[i] = dinv[base + q * 4 + i];
#pragma unroll
    for (int t = 0; t < 2; t++) {
        int nt = w * 2 + t;
        f32x4 acc = {0.f, 0.f, 0.f, 0.f};
#pragma unroll
        for (int kc = 0; kc < 4; kc++) {
            bf16x8 Bf = *(const bf16x8*)(Wt + ((nt * 16 + r) << 7) + kc * 32 + q * 8);
            acc = __builtin_amdgcn_mfma_f32_16x16x32_bf16(Af[kc], Bf, acc, 0, 0, 0);
        }
#pragma unroll
        for (int i = 0; i < 4; i++)
            hw_out[(size_t)(base + q * 4 + i) * DIM + nt * 16 + r] = f2bf(dv[i] * acc[i]);
    }
}

// ---- final layer: relu(dv*agg+b) -> f32 out, 4 nodes per wave --------------
__global__ __launch_bounds__(256) void k_agg_out(const u16* __restrict__ hw_in,
                                                 const int* __restrict__ rp8,
                                                 const int* __restrict__ recs,
                                                 const float* __restrict__ dinv,
                                                 const float* __restrict__ bias,
                                                 float* __restrict__ out) {
    int lane = threadIdx.x & 63;
    int w = threadIdx.x >> 6;
    int g = lane >> 4, r = lane & 15;
    int v0 = blockIdx.x * 16 + w * 4;  // grid 3125 exact
    f32x2 A0[4], A1[4], A2[4], A3[4];
    agg_quad(hw_in, rp8, recs, v0, g, r, A0, A1, A2, A3);
    float4 dvq = *(const float4*)(dinv + v0);
    combine_scale2(dvq.x, bias, r, A0);
    combine_scale2(dvq.y, bias, r, A1);
    combine_scale2(dvq.z, bias, r, A2);
    combine_scale2(dvq.w, bias, r, A3);
    if (g == 0) {
        f32x2* a[4] = {A0, A1, A2, A3};
#pragma unroll
        for (int i = 0; i < 4; i++) {
            float4* p = (float4*)(out + (size_t)(v0 + i) * DIM + r * 8);
            p[0] = make_float4(a[i][0].x, a[i][0].y, a[i][1].x, a[i][1].y);
            p[1] = make_float4(a[i][2].x, a[i][2].y, a[i][3].x, a[i][3].y);
        }
    }
}

// ---- launch ----------------------------------------------------------------

extern "C" void kernel_launch(void* const* d_in, const int* in_sizes, int n_in,
                              void* d_out, int out_size, void* d_ws, size_t ws_size,
                              hipStream_t stream) {
    const float* x = (const float*)d_in[0];
    const int* ei = (const int*)d_in[1];
    const float* W0 = (const float*)d_in[2];
    const float* b0 = (const float*)d_in[3];
    const float* W1 = (const float*)d_in[4];
    const float* b1 = (const float*)d_in[5];
    const float* W2 = (const float*)d_in[6];
    const float* b2 = (const float*)d_in[7];

    char* ws = (char*)d_ws;
    size_t off = 0;
    auto alloc = [&](size_t bytes) -> void* {
        void* p = ws + off;
        off += (bytes + 511) & ~(size_t)511;
        return p;
    };
    int* deg = (int*)alloc(NN * 4);  // zeroed
    size_t zbytes = off;
    int* rank = (int*)alloc((size_t)NE * 4);
    int* recs = (int*)alloc((size_t)NEPAD * 4);
    float* dinv = (float*)alloc(NN * 4);
    int* rp8 = (int*)alloc((NN + 8) * 4);
    int* bsum = (int*)alloc(256 * 4);
    u16* Wt = (u16*)alloc(3 * 128 * 128 * 2);
    u16* hwA = (u16*)alloc((size_t)(NN + 1) * DIM * 2);  // +1 sentinel row
    u16* hwB = (u16*)alloc((size_t)(NN + 1) * DIM * 2);

    hipMemsetAsync(ws, 0, zbytes, stream);
    k_count<<<NB_E2 + 192, 256, 0, stream>>>(ei, deg, rank, W0, W1, W2, Wt);
    k_scanA<<<NB_N, 256, 0, stream>>>(deg, rp8, bsum);
    k_scanC<<<NB_N, 256, 0, stream>>>(deg, rp8, bsum, dinv);
    k_fill<<<NB_FILL, 256, 0, stream>>>(ei, rp8, rank, deg, recs, x, Wt, dinv,
                                        hwA, hwB);
    k_agg_gemm<<<TILES, 256, 0, stream>>>(hwA, rp8, recs, dinv, b0,
                                          Wt + 16384, hwB);
    k_agg_gemm<<<TILES, 256, 0, stream>>>(hwB, rp8, recs, dinv, b1,
                                          Wt + 32768, hwA);
    k_agg_out<<<3125, 256, 0, stream>>>(hwA, rp8, recs, dinv, b2,
                                        (float*)d_out);
}

// Round 4
// 238.380 us; speedup vs baseline: 1.0452x; 1.0452x over previous
//
#include <hip/hip_runtime.h>

#define NN 50000
#define NE 600000
#define DIM 128
#define NB_N 196   // ceil(50000/256)
#define NB_E2 1172 // ceil(300000/256) edge-pair blocks
#define TILES 3125 // 50000/16
#define ROWW 136   // LDS row pitch in u16 (128 + 8 pad)
#define WPITCH 136 // LDS W0 pitch in u16 (16B-aligned rows)
#define NEPAD (NE + 16 * NN + 64)  // rows padded to multiple of 16, min 16

// k_count block roles: edges | W1/W2 cast | layer-1 GEMM (x @ W0 -> hF, unscaled)
#define CB_CAST0 NB_E2              // 1172
#define CB_GEMM0 (NB_E2 + 128)      // 1300
#define NB_GEMM 782                 // ceil(3125/4)
#define NB_CNT (CB_GEMM0 + NB_GEMM) // 2082

// k_scanC block roles: scan-apply+dinv | sentinel zero | hF*dinv -> hwA bf16
#define SC_SENT NB_N                // 196
#define SC_SCALE0 (NB_N + 1)        // 197
#define NB_SCALE 6250               // 50000 rows / 8 rows per block
#define NB_SCANC (SC_SCALE0 + NB_SCALE)

// k_fill block roles: CSR fill | pad sentinels
#define NB_FILL (NB_E2 + NB_N)      // 1368

typedef unsigned short u16;
typedef unsigned int u32;
typedef __attribute__((ext_vector_type(8))) short bf16x8;
typedef __attribute__((ext_vector_type(4))) float f32x4;

__device__ __forceinline__ u16 f2bf(float f) {
    u32 u = __builtin_bit_cast(u32, f);
    u32 r = (u + 0x7FFFu + ((u >> 16) & 1u)) >> 16;
    return (u16)r;
}
__device__ __forceinline__ float bflo(u32 w) { return __builtin_bit_cast(float, w << 16); }
__device__ __forceinline__ float bfhi(u32 w) { return __builtin_bit_cast(float, w & 0xffff0000u); }
__device__ __forceinline__ int pad16(int d) {
    int p = (d + 15) & ~15;
    return p < 16 ? 16 : p;
}

// ---- count + rank + W1/W2 cast + layer-1 GEMM ------------------------------
// blocks [0,1172): 2 edges/thread: in-degree count; rank[e] = slot in dst row
// blocks [1172,1300): Wt[l][n][k] = bf16(Wl[k][n]) for l=1,2
// blocks [1300,2082): hF[v] = f32(bf16(x[v]) @ bf16(W0))  (unscaled)
__global__ __launch_bounds__(256) void k_count(const int* __restrict__ ei,
                                               int* __restrict__ deg,
                                               int* __restrict__ rank,
                                               const float* __restrict__ W0,
                                               const float* __restrict__ W1,
                                               const float* __restrict__ W2,
                                               u16* __restrict__ Wt,
                                               const float* __restrict__ x,
                                               float* __restrict__ hF) {
    __shared__ u16 ldsW[128 * WPITCH];
    int b = blockIdx.x;
    if (b < NB_E2) {  // edge pairs
        __shared__ int s64;
        if (threadIdx.x == 0) {
            int o = 0;
#pragma unroll
            for (int j = 0; j < 16; j++) o |= ei[2 * j + 1];  // int64 => high words 0
            s64 = (o == 0);
        }
        __syncthreads();
        int p = b * 256 + threadIdx.x;  // edge pair index
        int ebase = 2 * p;
        if (ebase >= NE) return;
        int d0, d1;
        if (s64) {
            int4 dd = *(const int4*)(ei + 2 * (NE + ebase));
            d0 = dd.x; d1 = dd.z;
        } else {
            int2 dd = *(const int2*)(ei + NE + ebase);
            d0 = dd.x; d1 = dd.y;
        }
        int r0 = atomicAdd(&deg[d0], 1);
        int r1 = atomicAdd(&deg[d1], 1);
        *(int2*)(rank + ebase) = make_int2(r0, r1);
        return;
    }
    if (b < CB_GEMM0) {  // W1/W2 cast: 128 blocks x 256 = 32768 = 2*16384
        int idx = (b - CB_CAST0) * 256 + threadIdx.x;
        int l = idx >> 14, rem = idx & 16383;
        int n = rem >> 7, k = rem & 127;
        const float* W = (l == 0) ? W1 : W2;
        Wt[16384 + idx] = f2bf(W[k * 128 + n]);
        return;
    }
    // ---- layer-1 GEMM: stage W0 transposed+cast into LDS, then MFMA -------
    int gb = b - CB_GEMM0;
    for (int i = 0; i < 64; i++) {
        int j = i * 256 + threadIdx.x;  // 16384 elems, coalesced
        int k = j >> 7, n = j & 127;
        ldsW[n * WPITCH + k] = f2bf(W0[j]);
    }
    __syncthreads();
    int lane = threadIdx.x & 63;
    int tile = gb * 4 + (threadIdx.x >> 6);
    if (tile >= TILES) return;
    int r = lane & 15, q = lane >> 4;
    long rowbase = (long)tile * 16;
    bf16x8 Af[4];
#pragma unroll
    for (int kc = 0; kc < 4; kc++) {
        const float4* p = (const float4*)(x + (rowbase + r) * 128 + kc * 32 + q * 8);
        float4 t0 = p[0], t1 = p[1];
        bf16x8 a;
        a[0] = (short)f2bf(t0.x); a[1] = (short)f2bf(t0.y);
        a[2] = (short)f2bf(t0.z); a[3] = (short)f2bf(t0.w);
        a[4] = (short)f2bf(t1.x); a[5] = (short)f2bf(t1.y);
        a[6] = (short)f2bf(t1.z); a[7] = (short)f2bf(t1.w);
        Af[kc] = a;
    }
#pragma unroll
    for (int nt = 0; nt < 8; nt++) {
        f32x4 acc = {0.f, 0.f, 0.f, 0.f};
#pragma unroll
        for (int kc = 0; kc < 4; kc++) {
            bf16x8 Bf = *(const bf16x8*)(ldsW + (nt * 16 + r) * WPITCH + kc * 32 + q * 8);
            acc = __builtin_amdgcn_mfma_f32_16x16x32_bf16(Af[kc], Bf, acc, 0, 0, 0);
        }
#pragma unroll
        for (int i = 0; i < 4; i++)
            hF[(rowbase + q * 4 + i) * 128 + nt * 16 + r] = acc[i];
    }
}

// ---- scanA: per-block exclusive scan of pad16(deg), raw block sums --------
__global__ __launch_bounds__(256) void k_scanA(const int* __restrict__ deg,
                                               int* __restrict__ rp8,
                                               int* __restrict__ bsum) {
    __shared__ int buf[256];
    int t = threadIdx.x, i = blockIdx.x * 256 + t;
    int v = (i < NN) ? pad16(deg[i]) : 0;
    buf[t] = v;
    __syncthreads();
    for (int off = 1; off < 256; off <<= 1) {
        int x = (t >= off) ? buf[t - off] : 0;
        __syncthreads();
        buf[t] += x;
        __syncthreads();
    }
    if (i < NN) rp8[i] = buf[t] - v;
    if (t == 255) bsum[blockIdx.x] = buf[255];
}

// ---- scanC: apply block prefix + dinv | sentinel zero | scale hF -> hwA ----
__global__ __launch_bounds__(256) void k_scanC(const int* __restrict__ deg,
                                               int* __restrict__ rp8,
                                               const int* __restrict__ bsum,
                                               float* __restrict__ dinv,
                                               const float* __restrict__ hF,
                                               u16* __restrict__ hwA,
                                               u16* __restrict__ hwB) {
    int b = blockIdx.x;
    if (b < NB_N) {  // scan apply + dinv
        __shared__ int soff, stot;
        if (threadIdx.x < 64) {
            int accP = 0, accT = 0;
            for (int j = threadIdx.x; j < NB_N; j += 64) {
                int v = bsum[j];
                accT += v;
                if (j < b) accP += v;
            }
            for (int off = 1; off < 64; off <<= 1) {
                accP += __shfl_xor(accP, off, 64);
                accT += __shfl_xor(accT, off, 64);
            }
            if (threadIdx.x == 0) { soff = accP; stot = accT; }
        }
        __syncthreads();
        int i = b * 256 + threadIdx.x;
        if (i < NN) {
            rp8[i] += soff;
            dinv[i] = rsqrtf((float)(deg[i] + 1));  // +1 self loop
        }
        if (i == 0) rp8[NN] = stot;
        return;
    }
    if (b == SC_SENT) {  // zero sentinel rows (256 B each)
        if (threadIdx.x < 64) {
            ((u32*)(hwA + (size_t)NN * DIM))[threadIdx.x] = 0;
        } else if (threadIdx.x < 128) {
            ((u32*)(hwB + (size_t)NN * DIM))[threadIdx.x - 64] = 0;
        }
        return;
    }
    // scale: hwA[row] = bf16(dinv[row] * hF[row]); 8 rows/block, 32 thr/row
    int idx = (b - SC_SCALE0) * 256 + threadIdx.x;
    int row = idx >> 5, part = idx & 31;
    float dv = rsqrtf((float)(deg[row] + 1));
    float4 v = *(const float4*)(hF + (size_t)row * 128 + part * 4);
    u32 lo = (u32)f2bf(dv * v.x) | ((u32)f2bf(dv * v.y) << 16);
    u32 hi = (u32)f2bf(dv * v.z) | ((u32)f2bf(dv * v.w) << 16);
    *(uint2*)(hwA + (size_t)row * 128 + part * 4) = make_uint2(lo, hi);
}

// ---- fill CSR + pad sentinels ---------------------------------------------
__global__ __launch_bounds__(256) void k_fill(const int* __restrict__ ei,
                                              const int* __restrict__ rp8,
                                              const int* __restrict__ rank,
                                              const int* __restrict__ deg,
                                              int* __restrict__ recs) {
    int b = blockIdx.x;
    if (b < NB_E2) {  // CSR fill, 2 edges/thread (no atomics: rank precomputed)
        __shared__ int s64;
        if (threadIdx.x == 0) {
            int o = 0;
#pragma unroll
            for (int j = 0; j < 16; j++) o |= ei[2 * j + 1];
            s64 = (o == 0);
        }
        __syncthreads();
        int p = b * 256 + threadIdx.x;
        int ebase = 2 * p;
        if (ebase >= NE) return;
        int s0, s1, d0, d1;
        if (s64) {
            int4 ss = *(const int4*)(ei + 2 * ebase);
            int4 dd = *(const int4*)(ei + 2 * (NE + ebase));
            s0 = ss.x; s1 = ss.z; d0 = dd.x; d1 = dd.z;
        } else {
            int2 ss = *(const int2*)(ei + ebase);
            int2 dd = *(const int2*)(ei + NE + ebase);
            s0 = ss.x; s1 = ss.y; d0 = dd.x; d1 = dd.y;
        }
        int2 rk = *(const int2*)(rank + ebase);
        recs[rp8[d0] + rk.x] = s0;
        recs[rp8[d1] + rk.y] = s1;
        return;
    }
    // pad entries -> sentinel node NN
    int i = (b - NB_E2) * 256 + threadIdx.x;
    if (i < NN) {
        int rp = rp8[i], d = deg[i], p = pad16(d);
        for (int j = d; j < p; j++) recs[rp + j] = NN;
    }
}

// ---- aggregation core: wave = 2 nodes; group g handles edges {4g..4g+3}
// per 16-entry chunk (pad16 CSR). Pads read sentinel row NN (zeros).
__device__ __forceinline__ void add8(float* a, uint4 u) {
    a[0] += bflo(u.x); a[1] += bfhi(u.x);
    a[2] += bflo(u.y); a[3] += bfhi(u.y);
    a[4] += bflo(u.z); a[5] += bfhi(u.z);
    a[6] += bflo(u.w); a[7] += bfhi(u.w);
}

__device__ __forceinline__ void agg_pair(const u16* __restrict__ hw,
                                         const int* __restrict__ rp8,
                                         const int* __restrict__ recs,
                                         int va, int vb, int g, int r,
                                         float* A, float* B) {
    uint4 sva = *(const uint4*)(hw + (size_t)va * DIM + r * 8);
    uint4 svb = *(const uint4*)(hw + (size_t)vb * DIM + r * 8);
    float m = (g == 0) ? 1.0f : 0.0f;  // self term counted once
    A[0] = m * bflo(sva.x); A[1] = m * bfhi(sva.x);
    A[2] = m * bflo(sva.y); A[3] = m * bfhi(sva.y);
    A[4] = m * bflo(sva.z); A[5] = m * bfhi(sva.z);
    A[6] = m * bflo(sva.w); A[7] = m * bfhi(sva.w);
    B[0] = m * bflo(svb.x); B[1] = m * bfhi(svb.x);
    B[2] = m * bflo(svb.y); B[3] = m * bfhi(svb.y);
    B[4] = m * bflo(svb.z); B[5] = m * bfhi(svb.z);
    B[6] = m * bflo(svb.w); B[7] = m * bfhi(svb.w);

    int ea = rp8[va], enda = rp8[va + 1];
    int eb = rp8[vb], endb = rp8[vb + 1];
    const int go = 4 * g;
    int4 qa = *(const int4*)(recs + ea + go);
    int4 qb = *(const int4*)(recs + eb + go);
    while (ea < enda || eb < endb) {
        int sa0 = (ea < enda) ? qa.x : NN;
        int sa1 = (ea < enda) ? qa.y : NN;
        int sa2 = (ea < enda) ? qa.z : NN;
        int sa3 = (ea < enda) ? qa.w : NN;
        int sb0 = (eb < endb) ? qb.x : NN;
        int sb1 = (eb < endb) ? qb.y : NN;
        int sb2 = (eb < endb) ? qb.z : NN;
        int sb3 = (eb < endb) ? qb.w : NN;
        uint4 ua0 = *(const uint4*)(hw + (size_t)(u32)sa0 * DIM + r * 8);
        uint4 ua1 = *(const uint4*)(hw + (size_t)(u32)sa1 * DIM + r * 8);
        uint4 ua2 = *(const uint4*)(hw + (size_t)(u32)sa2 * DIM + r * 8);
        uint4 ua3 = *(const uint4*)(hw + (size_t)(u32)sa3 * DIM + r * 8);
        uint4 ub0 = *(const uint4*)(hw + (size_t)(u32)sb0 * DIM + r * 8);
        uint4 ub1 = *(const uint4*)(hw + (size_t)(u32)sb1 * DIM + r * 8);
        uint4 ub2 = *(const uint4*)(hw + (size_t)(u32)sb2 * DIM + r * 8);
        uint4 ub3 = *(const uint4*)(hw + (size_t)(u32)sb3 * DIM + r * 8);
        ea += 16; eb += 16;
        int4 qa_n = *(const int4*)(recs + min(ea, enda - 16) + go);
        int4 qb_n = *(const int4*)(recs + min(eb, endb - 16) + go);
        add8(A, ua0); add8(A, ua1); add8(A, ua2); add8(A, ua3);
        add8(B, ub0); add8(B, ub1); add8(B, ub2); add8(B, ub3);
        qa = qa_n; qb = qb_n;
    }
}

// combine groups, scale by dinv[d], + bias, relu
__device__ __forceinline__ void combine_scale(float dv, const float* bias, int r,
                                              float* acc) {
#pragma unroll
    for (int j = 0; j < 8; j++) {
        acc[j] += __shfl_xor(acc[j], 16, 64);
        acc[j] += __shfl_xor(acc[j], 32, 64);
    }
    float4 b0 = ((const float4*)bias)[2 * r];
    float4 b1 = ((const float4*)bias)[2 * r + 1];
    acc[0] = fmaxf(fmaf(dv, acc[0], b0.x), 0.f);
    acc[1] = fmaxf(fmaf(dv, acc[1], b0.y), 0.f);
    acc[2] = fmaxf(fmaf(dv, acc[2], b0.z), 0.f);
    acc[3] = fmaxf(fmaf(dv, acc[3], b0.w), 0.f);
    acc[4] = fmaxf(fmaf(dv, acc[4], b1.x), 0.f);
    acc[5] = fmaxf(fmaf(dv, acc[5], b1.y), 0.f);
    acc[6] = fmaxf(fmaf(dv, acc[6], b1.z), 0.f);
    acc[7] = fmaxf(fmaf(dv, acc[7], b1.w), 0.f);
}

// ---- fused: h = relu(dv*agg+b) -> LDS tile -> hw_out = dinv * (h @ W) ------
__global__ __launch_bounds__(256) void k_agg_gemm(const u16* __restrict__ hw_in,
                                                  const int* __restrict__ rp8,
                                                  const int* __restrict__ recs,
                                                  const float* __restrict__ dinv,
                                                  const float* __restrict__ bias,
                                                  const u16* __restrict__ Wt,
                                                  u16* __restrict__ hw_out) {
    __shared__ u16 sm[16 * ROWW];
    int lane = threadIdx.x & 63;
    int w = threadIdx.x >> 6;
    int g = lane >> 4, r = lane & 15;
    int base = blockIdx.x * 16;
#pragma unroll
    for (int p = 0; p < 2; p++) {
        int rowa = w * 4 + 2 * p;
        int va = base + rowa;
        float A[8], B[8];
        agg_pair(hw_in, rp8, recs, va, va + 1, g, r, A, B);
        combine_scale(dinv[va], bias, r, A);
        combine_scale(dinv[va + 1], bias, r, B);
        if (g == 0) {
            uint4 pk;
            pk.x = (u32)f2bf(A[0]) | ((u32)f2bf(A[1]) << 16);
            pk.y = (u32)f2bf(A[2]) | ((u32)f2bf(A[3]) << 16);
            pk.z = (u32)f2bf(A[4]) | ((u32)f2bf(A[5]) << 16);
            pk.w = (u32)f2bf(A[6]) | ((u32)f2bf(A[7]) << 16);
            *(uint4*)(sm + rowa * ROWW + r * 8) = pk;
            pk.x = (u32)f2bf(B[0]) | ((u32)f2bf(B[1]) << 16);
            pk.y = (u32)f2bf(B[2]) | ((u32)f2bf(B[3]) << 16);
            pk.z = (u32)f2bf(B[4]) | ((u32)f2bf(B[5]) << 16);
            pk.w = (u32)f2bf(B[6]) | ((u32)f2bf(B[7]) << 16);
            *(uint4*)(sm + (rowa + 1) * ROWW + r * 8) = pk;
        }
    }
    __syncthreads();
    // GEMM: 16x128 LDS tile @ 128x128 W; wave w does n-tiles {2w, 2w+1}
    int q = lane >> 4;
    bf16x8 Af[4];
#pragma unroll
    for (int kc = 0; kc < 4; kc++)
        Af[kc] = *(const bf16x8*)(sm + r * ROWW + kc * 32 + q * 8);
    float dv[4];
#pragma unroll
    for (int i = 0; i < 4; i++) dv[i] = dinv[base + q * 4 + i];
#pragma unroll
    for (int t = 0; t < 2; t++) {
        int nt = w * 2 + t;
        f32x4 acc = {0.f, 0.f, 0.f, 0.f};
#pragma unroll
        for (int kc = 0; kc < 4; kc++) {
            bf16x8 Bf = *(const bf16x8*)(Wt + ((nt * 16 + r) << 7) + kc * 32 + q * 8);
            acc = __builtin_amdgcn_mfma_f32_16x16x32_bf16(Af[kc], Bf, acc, 0, 0, 0);
        }
#pragma unroll
        for (int i = 0; i < 4; i++)
            hw_out[(size_t)(base + q * 4 + i) * DIM + nt * 16 + r] = f2bf(dv[i] * acc[i]);
    }
}

// ---- final layer: relu(dv*agg+b) -> f32 out, 2 nodes per wave --------------
__global__ __launch_bounds__(256) void k_agg_out(const u16* __restrict__ hw_in,
                                                 const int* __restrict__ rp8,
                                                 const int* __restrict__ recs,
                                                 const float* __restrict__ dinv,
                                                 const float* __restrict__ bias,
                                                 float* __restrict__ out) {
    int lane = threadIdx.x & 63;
    int w = threadIdx.x >> 6;
    int g = lane >> 4, r = lane & 15;
    int va = blockIdx.x * 8 + w * 2;  // grid 6250 exact
    float A[8], B[8];
    agg_pair(hw_in, rp8, recs, va, va + 1, g, r, A, B);
    combine_scale(dinv[va], bias, r, A);
    combine_scale(dinv[va + 1], bias, r, B);
    if (g == 0) {
        float4* p = (float4*)(out + (size_t)va * DIM + r * 8);
        p[0] = make_float4(A[0], A[1], A[2], A[3]);
        p[1] = make_float4(A[4], A[5], A[6], A[7]);
        p = (float4*)(out + (size_t)(va + 1) * DIM + r * 8);
        p[0] = make_float4(B[0], B[1], B[2], B[3]);
        p[1] = make_float4(B[4], B[5], B[6], B[7]);
    }
}

// ---- launch ----------------------------------------------------------------

extern "C" void kernel_launch(void* const* d_in, const int* in_sizes, int n_in,
                              void* d_out, int out_size, void* d_ws, size_t ws_size,
                              hipStream_t stream) {
    const float* x = (const float*)d_in[0];
    const int* ei = (const int*)d_in[1];
    const float* W0 = (const float*)d_in[2];
    const float* b0 = (const float*)d_in[3];
    const float* W1 = (const float*)d_in[4];
    const float* b1 = (const float*)d_in[5];
    const float* W2 = (const float*)d_in[6];
    const float* b2 = (const float*)d_in[7];

    char* ws = (char*)d_ws;
    size_t off = 0;
    auto alloc = [&](size_t bytes) -> void* {
        void* p = ws + off;
        off += (bytes + 511) & ~(size_t)511;
        return p;
    };
    int* deg = (int*)alloc(NN * 4);  // zeroed
    size_t zbytes = off;
    int* rank = (int*)alloc((size_t)NE * 4);
    int* recs = (int*)alloc((size_t)NEPAD * 4);
    float* dinv = (float*)alloc(NN * 4);
    int* rp8 = (int*)alloc((NN + 8) * 4);
    int* bsum = (int*)alloc(256 * 4);
    u16* Wt = (u16*)alloc(3 * 128 * 128 * 2);
    u16* hwA = (u16*)alloc((size_t)(NN + 1) * DIM * 2);  // +1 sentinel row
    u16* hwB = (u16*)alloc((size_t)(NN + 1) * DIM * 2);
    float* hF = (float*)alloc((size_t)NN * DIM * 4);     // unscaled layer-1 f32

    hipMemsetAsync(ws, 0, zbytes, stream);
    k_count<<<NB_CNT, 256, 0, stream>>>(ei, deg, rank, W0, W1, W2, Wt, x, hF);
    k_scanA<<<NB_N, 256, 0, stream>>>(deg, rp8, bsum);
    k_scanC<<<NB_SCANC, 256, 0, stream>>>(deg, rp8, bsum, dinv, hF, hwA, hwB);
    k_fill<<<NB_FILL, 256, 0, stream>>>(ei, rp8, rank, deg, recs);
    k_agg_gemm<<<TILES, 256, 0, stream>>>(hwA, rp8, recs, dinv, b0,
                                          Wt + 16384, hwB);
    k_agg_gemm<<<TILES, 256, 0, stream>>>(hwB, rp8, recs, dinv, b1,
                                          Wt + 32768, hwA);
    k_agg_out<<<6250, 256, 0, stream>>>(hwA, rp8, recs, dinv, b2,
                                        (float*)d_out);
}